// Round 15
// baseline (288.786 us; speedup 1.0000x reference)
//
#include <hip/hip_runtime.h>
#include <math.h>

#define CC    144
#define WW    9225
#define KWW   10
#define FF    64
#define H1N   128
#define CONVN (WW - KWW + 1)   // 9216
#define CFN   (CC * FF)        // 9216
#define CATN  (CFN + CONVN)    // 18432
#define FCB2  (CC * 8)         // 1152 fc blocks: (channel c, f-group g of 8)
#define CONVB (CONVN / 256)    // 36 conv blocks
#define TOTB  (FCB2 + CONVB)   // 1188
#define NV4   36               // 36 iters * 64 lanes * 4 floats = 9216
#define NTAIL 9                // 9225 - 9216

typedef float f32x4  __attribute__((ext_vector_type(4)));
typedef float f32x4u __attribute__((ext_vector_type(4), aligned(4)));

// ---------------------------------------------------------------------------
// v14: FULLY FUSED. fc/conv blocks (v13 bodies) fold their outputs directly
// into pre1[128] = W1 @ concat via per-block LDS partials + device-scope
// atomicAdd (concat never materialized; k_layer1/k_final launches eliminated).
// Ticket counter: the LAST block applies b1/relu/W2/b2/sigmoid -> out.
// The W-stream read ceiling (~5.1 TB/s, 6 falsified theories) is taken as
// given; this attacks the only remaining serial term (launch + layer1 tail).
// ---------------------------------------------------------------------------
__global__ __launch_bounds__(256) void k_zero(float* pre1, unsigned* counter) {
    const int tid = threadIdx.x;
    if (tid < H1N) pre1[tid] = 0.f;
    if (tid == 0) *counter = 0u;
}

__global__ __launch_bounds__(256) void k_fused(
    const float* __restrict__ x,     // [C, W]
    const float* __restrict__ Wfc,   // [C, F, W]
    const float* __restrict__ bfc,   // [C, F]
    const float* __restrict__ Kc,    // [C, KW]
    const float* __restrict__ bconv, // [1]
    const float* __restrict__ W1,    // [H1, CAT]
    const float* __restrict__ b1,    // [H1]
    const float* __restrict__ W2,    // [1, H1]
    const float* __restrict__ b2,    // [1]
    float* __restrict__ pre1,        // [H1] ws, zeroed by k_zero
    unsigned* __restrict__ counter,  // [1]  ws, zeroed by k_zero
    float* __restrict__ out)         // [1]
{
    __shared__ float kc[CC * KWW];   // conv blocks only (5.76 KB)
    __shared__ float p1[4][H1N];     // per-wave layer1 partials (2 KB)
    __shared__ float convout[256];
    __shared__ float smr[4];
    __shared__ unsigned lastFlag;

    const int bid  = blockIdx.x;
    const int tid  = threadIdx.x;
    const int wave = tid >> 6, lane = tid & 63;

    if (bid < FCB2) {
        // ================= fc: 4 waves, 2 rows/wave, all-nt float4 =========
        const int c  = bid >> 3, g = bid & 7;
        const int f0 = g * 8 + wave * 2;
        const int r0 = (c << 6) + f0;
        const f32x4u* __restrict__ w0v = (const f32x4u*)(Wfc + (size_t)r0 * WW);
        const f32x4u* __restrict__ w1v = (const f32x4u*)(Wfc + (size_t)(r0 + 1) * WW);
        const f32x4u* __restrict__ xv  = (const f32x4u*)(x + (size_t)c * WW);

        float a0 = 0.f, a1 = 0.f;
        #pragma unroll 4
        for (int i = 0; i < NV4; ++i) {
            const int q = i * 64 + lane;
            const f32x4 xq  = xv[q];
            const f32x4 wq0 = __builtin_nontemporal_load(w0v + q);
            const f32x4 wq1 = __builtin_nontemporal_load(w1v + q);
            a0 += wq0.x * xq.x + wq0.y * xq.y + wq0.z * xq.z + wq0.w * xq.w;
            a1 += wq1.x * xq.x + wq1.y * xq.y + wq1.z * xq.z + wq1.w * xq.w;
        }
        if (lane < NTAIL) {
            const int e = NV4 * 256 + lane;
            const float* __restrict__ xr = x + (size_t)c * WW;
            const float* __restrict__ wb = Wfc + (size_t)r0 * WW;
            a0 = fmaf(wb[e],      xr[e], a0);
            a1 = fmaf(wb[WW + e], xr[e], a1);
        }
        #pragma unroll
        for (int off = 32; off; off >>= 1) {
            a0 += __shfl_xor(a0, off, 64);
            a1 += __shfl_xor(a1, off, 64);
        }
        a0 += bfc[r0];
        a1 += bfc[r0 + 1];

        // layer1 fold: p1[wave][h] = a0*W1[h][r0] + a1*W1[h][r0+1]
        {
            const float* __restrict__ w1c = W1 + r0;   // column base
            const size_t o0 = (size_t)lane * CATN;
            const size_t o1 = (size_t)(lane + 64) * CATN;
            p1[wave][lane]      = a0 * w1c[o0] + a1 * w1c[o0 + 1];
            p1[wave][lane + 64] = a0 * w1c[o1] + a1 * w1c[o1 + 1];
        }
        __syncthreads();
        if (tid < H1N)
            atomicAdd(&pre1[tid],
                      p1[0][tid] + p1[1][tid] + p1[2][tid] + p1[3][tid]);
    } else {
        // ================= conv: 256 positions/block =======================
        for (int i = tid; i < CC * KWW; i += 256) kc[i] = Kc[i];
        __syncthreads();
        const int pbase = (bid - FCB2) * 256;
        const int p = pbase + tid;
        float acc = bconv[0];
        for (int c2 = 0; c2 < CC; ++c2) {
            const float* __restrict__ xr = x + (size_t)c2 * WW + p;
            const float* __restrict__ kr = kc + c2 * KWW;
            #pragma unroll
            for (int k = 0; k < KWW; ++k)
                acc = fmaf(xr[k], kr[k], acc);
        }
        convout[tid] = acc;
        __syncthreads();
        // layer1 fold: thread (h = tid&127, half = tid>>7) sums 128 j's
        {
            const int h = tid & 127, half = tid >> 7;
            const float* __restrict__ wrow =
                W1 + (size_t)h * CATN + CFN + pbase + half * 128;
            const float* __restrict__ cvo = convout + half * 128;
            float s = 0.f;
            #pragma unroll 4
            for (int j = 0; j < 128; ++j)
                s = fmaf(cvo[j], wrow[j], s);
            p1[half][h] = s;
        }
        __syncthreads();
        if (tid < H1N)
            atomicAdd(&pre1[tid], p1[0][tid] + p1[1][tid]);
    }

    // ================= ticket: last block computes the head ================
    __threadfence();
    __syncthreads();
    if (tid == 0) {
        const unsigned old = atomicAdd(counter, 1u);
        lastFlag = (old == TOTB - 1) ? 1u : 0u;
    }
    __syncthreads();
    if (lastFlag) {
        float v = 0.f;
        if (tid < H1N) {
            const float pv = atomicAdd(&pre1[tid], 0.f);   // coherent read
            v = fmaxf(pv + b1[tid], 0.f) * W2[tid];
        }
        #pragma unroll
        for (int off = 32; off; off >>= 1)
            v += __shfl_xor(v, off, 64);
        if (lane == 0) smr[wave] = v;
        __syncthreads();
        if (tid == 0) {
            float z = smr[0] + smr[1] + smr[2] + smr[3];
            z = fmaxf(z + b2[0], 0.f);
            out[0] = 1.f / (1.f + expf(-z));
        }
    }
}

extern "C" void kernel_launch(void* const* d_in, const int* in_sizes, int n_in,
                              void* d_out, int out_size, void* d_ws, size_t ws_size,
                              hipStream_t stream) {
    const float* x     = (const float*)d_in[0];
    const float* Wfc   = (const float*)d_in[1];
    const float* bfc   = (const float*)d_in[2];
    const float* Kc    = (const float*)d_in[3];
    const float* bconv = (const float*)d_in[4];
    const float* W1    = (const float*)d_in[5];
    const float* b1    = (const float*)d_in[6];
    const float* W2    = (const float*)d_in[7];
    const float* b2    = (const float*)d_in[8];
    float* out = (float*)d_out;

    float*    pre1    = (float*)d_ws;            // [128]
    unsigned* counter = (unsigned*)(pre1 + H1N); // [1]

    k_zero <<<1, 256, 0, stream>>>(pre1, counter);
    k_fused<<<TOTB, 256, 0, stream>>>(x, Wfc, bfc, Kc, bconv,
                                      W1, b1, W2, b2, pre1, counter, out);
}

// Round 16
// 81.774 us; speedup vs baseline: 3.5315x; 3.5315x over previous
//
#include <hip/hip_runtime.h>
#include <math.h>

#define CC    144
#define WW    9225
#define KWW   10
#define FF    64
#define H1N   128
#define CONVN (WW - KWW + 1)   // 9216
#define CFN   (CC * FF)        // 9216
#define CATN  (CFN + CONVN)    // 18432
#define FCB2  (CC * 8)         // 1152 fc blocks: (channel c, f-group g of 8)
#define NV4   36               // 36 iters * 64 lanes * 4 floats = 9216
#define NTAIL 9                // 9225 - 9216
#define HOTC  96               // c < HOTC: normal loads; c >= HOTC: nontemporal
#define L1B   256              // layer1 blocks (2 per h)

typedef float f32x4  __attribute__((ext_vector_type(4)));
typedef float f32x4u __attribute__((ext_vector_type(4), aligned(4)));

// ---------------------------------------------------------------------------
// Stage 1 = v9 exactly (best measured: 76.5us total): x row staged in LDS,
// each wave streams two contiguous Wfc rows as float4, HOTC nt split.
// Plus: bid 0 zeroes the ticket counter for stage 2 (visible at next launch).
//   blocks [0, FCB2): fc.  blocks [FCB2, FCB2+36): conv (256 positions each).
// ---------------------------------------------------------------------------
__global__ __launch_bounds__(256) void k_front_v9(
    const float* __restrict__ x,     // [C, W]
    const float* __restrict__ Wfc,   // [C, F, W]
    const float* __restrict__ bfc,   // [C, F]
    const float* __restrict__ Kc,    // [C, KW]
    const float* __restrict__ bconv, // [1]
    float* __restrict__ concat,      // [CATN]
    unsigned* __restrict__ counter)  // [1] ticket for stage 2
{
    __shared__ float smem[WW];       // 36.9 KB; conv blocks use first 1440
    const int bid = blockIdx.x;
    const int tid = threadIdx.x;

    if (bid == 0 && tid == 0) *counter = 0u;   // reset ticket each call

    if (bid < FCB2) {
        const int c = bid >> 3;                   // channel
        const int g = bid & 7;                    // f-group
        const float* __restrict__ xr = x + (size_t)c * WW;

        // ---- stage x row into LDS (coalesced)
        for (int i = tid; i < WW; i += 256) smem[i] = xr[i];
        __syncthreads();

        // ---- each wave: rows r0, r0+1 as float4 streams
        const int wave = tid >> 6;
        const int lane = tid & 63;
        const int f0   = g * 8 + wave * 2;
        const int r0   = (c << 6) + f0;           // fc row index
        const f32x4u* __restrict__ w0v =
            (const f32x4u*)(Wfc + (size_t)r0 * WW);
        const f32x4u* __restrict__ w1v =
            (const f32x4u*)(Wfc + (size_t)(r0 + 1) * WW);
        const f32x4* __restrict__ xv = (const f32x4*)smem;  // 16B-aligned

        float a0 = 0.f, a1 = 0.f;
        if (c < HOTC) {
            #pragma unroll 6
            for (int i = 0; i < NV4; ++i) {
                const int q = i * 64 + lane;      // float4 index
                const f32x4 xq = xv[q];
                const f32x4 wq0 = w0v[q];
                const f32x4 wq1 = w1v[q];
                a0 += wq0.x * xq.x + wq0.y * xq.y + wq0.z * xq.z + wq0.w * xq.w;
                a1 += wq1.x * xq.x + wq1.y * xq.y + wq1.z * xq.z + wq1.w * xq.w;
            }
        } else {
            #pragma unroll 6
            for (int i = 0; i < NV4; ++i) {
                const int q = i * 64 + lane;
                const f32x4 xq = xv[q];
                const f32x4 wq0 = __builtin_nontemporal_load(w0v + q);
                const f32x4 wq1 = __builtin_nontemporal_load(w1v + q);
                a0 += wq0.x * xq.x + wq0.y * xq.y + wq0.z * xq.z + wq0.w * xq.w;
                a1 += wq1.x * xq.x + wq1.y * xq.y + wq1.z * xq.z + wq1.w * xq.w;
            }
        }
        // tail: elements 9216..9224
        if (lane < NTAIL) {
            const int e = NV4 * 256 + lane;       // 9216 + lane
            const float xq = smem[e];
            const float* __restrict__ wb = Wfc + (size_t)r0 * WW;
            a0 = fmaf(wb[e],      xq, a0);
            a1 = fmaf(wb[WW + e], xq, a1);
        }

        // wave-only reduction — no LDS, no __syncthreads
        #pragma unroll
        for (int off = 32; off > 0; off >>= 1) {
            a0 += __shfl_xor(a0, off, 64);
            a1 += __shfl_xor(a1, off, 64);
        }
        if (lane == 0) {
            concat[r0]     = a0 + bfc[r0];
            concat[r0 + 1] = a1 + bfc[r0 + 1];
        }
    } else {
        // ---- conv: position p = (bid-FCB2)*256 + tid
        for (int i = tid; i < CC * KWW; i += 256) smem[i] = Kc[i];
        __syncthreads();

        const int p = (bid - FCB2) * 256 + tid;   // 36*256 == 9216 exactly
        float acc = bconv[0];
        for (int c = 0; c < CC; ++c) {
            const float* __restrict__ xr = x + (size_t)c * WW + p;
            const float* __restrict__ kr = smem + c * KWW;
            #pragma unroll
            for (int k = 0; k < KWW; ++k)
                acc = fmaf(xr[k], kr[k], acc);
        }
        concat[CFN + p] = acc;
    }
}

// ---------------------------------------------------------------------------
// Stage 2 v3: 256 blocks; block j = (h=j>>1, half=j&1) half-row partial dot
// -> partial[j]. Ticket: last block combines partials + b1/relu, dots W2,
// +b2/relu/sigmoid -> out. (k_final launch eliminated; no contended atomics —
// distinct partial[j] per block, one counter bump per block.)
// ---------------------------------------------------------------------------
__global__ __launch_bounds__(256) void k_layer1_v3(
    const float* __restrict__ W1,     // [H1, CAT]
    const float* __restrict__ concat, // [CAT]
    const float* __restrict__ b1,     // [H1]
    const float* __restrict__ W2,     // [1, H1]
    const float* __restrict__ b2,     // [1]
    float* __restrict__ partial,      // [256] ws
    unsigned* __restrict__ counter,   // [1]   ws (zeroed by stage 1)
    float* __restrict__ out)          // [1]
{
    __shared__ float sm[4];
    __shared__ unsigned lastFlag;
    const int j = blockIdx.x, tid = threadIdx.x;
    const int wave = tid >> 6, lane = tid & 63;
    const int h = j >> 1, half = j & 1;
    const f32x4* __restrict__ wr =
        (const f32x4*)(W1 + (size_t)h * CATN + half * (CATN / 2));
    const f32x4* __restrict__ cv =
        (const f32x4*)(concat + half * (CATN / 2));

    float acc = 0.f;
    for (int i = tid; i < CATN / 8; i += 256) {   // 9 iters
        const f32x4 a = wr[i];
        const f32x4 q = cv[i];
        acc += a.x * q.x + a.y * q.y + a.z * q.z + a.w * q.w;
    }
    #pragma unroll
    for (int off = 32; off > 0; off >>= 1)
        acc += __shfl_xor(acc, off, 64);
    if (lane == 0) sm[wave] = acc;
    __syncthreads();

    // ---- ticket (publish partial, then count)
    if (tid == 0) {
        partial[j] = sm[0] + sm[1] + sm[2] + sm[3];
        __threadfence();                          // make partial[j] visible
        const unsigned old = atomicAdd(counter, 1u);
        lastFlag = (old == (unsigned)(L1B - 1)) ? 1u : 0u;
    }
    __syncthreads();

    if (lastFlag) {
        float v = 0.f;
        if (tid < H1N) {
            const float p0 = atomicAdd(&partial[2 * tid], 0.f);      // coherent
            const float p1 = atomicAdd(&partial[2 * tid + 1], 0.f);  // reads
            v = fmaxf(p0 + p1 + b1[tid], 0.f) * W2[tid];
        }
        #pragma unroll
        for (int off = 32; off > 0; off >>= 1)
            v += __shfl_xor(v, off, 64);
        if (lane == 0) sm[wave] = v;
        __syncthreads();
        if (tid == 0) {
            float z = sm[0] + sm[1] + sm[2] + sm[3] + b2[0];
            z = fmaxf(z, 0.f);
            out[0] = 1.f / (1.f + expf(-z));
        }
    }
}

extern "C" void kernel_launch(void* const* d_in, const int* in_sizes, int n_in,
                              void* d_out, int out_size, void* d_ws, size_t ws_size,
                              hipStream_t stream) {
    const float* x     = (const float*)d_in[0];
    const float* Wfc   = (const float*)d_in[1];
    const float* bfc   = (const float*)d_in[2];
    const float* Kc    = (const float*)d_in[3];
    const float* bconv = (const float*)d_in[4];
    const float* W1    = (const float*)d_in[5];
    const float* b1    = (const float*)d_in[6];
    const float* W2    = (const float*)d_in[7];
    const float* b2    = (const float*)d_in[8];
    float* out = (float*)d_out;

    float*    concat  = (float*)d_ws;               // [CATN]
    float*    partial = concat + CATN;              // [256]
    unsigned* counter = (unsigned*)(partial + L1B); // [1]

    k_front_v9 <<<FCB2 + (CONVN / 256), 256, 0, stream>>>(
        x, Wfc, bfc, Kc, bconv, concat, counter);
    k_layer1_v3<<<L1B, 256, 0, stream>>>(
        W1, concat, b1, W2, b2, partial, counter, out);
}